// Round 1
// baseline (29290.961 us; speedup 1.0000x reference)
//
#include <hip/hip_runtime.h>
#include <math.h>

// Problem constants (B,T,N,D) = (2,64,512,256)
#define B_ 2
#define T_ 64
#define N_ 512
#define D_ 256
#define M_ (B_*T_*N_)            // 65536 rows for the GEMMs
#define PLANE ((size_t)M_*D_)    // 16777216 elements per output plane

// ---------------------------------------------------------------------------
// QR of 256x256 complex matrix, LAPACK zgeqr2/zung2r convention, fp64 internal.
// Single workgroup, 256 threads. A,Q column-major in global ws.
// ---------------------------------------------------------------------------
__global__ __launch_bounds__(256) void qr_kernel(
    const float* __restrict__ ure_raw, const float* __restrict__ uim_raw,
    double2* __restrict__ A, double2* __restrict__ Q, double2* __restrict__ tau,
    float* __restrict__ u_re, float* __restrict__ u_im)
{
  const int tid = threadIdx.x;
  __shared__ double red[256];
  __shared__ double2 sv[256];
  __shared__ double s_beta, s_taur, s_taui, s_sclr, s_scli;
  __shared__ int s_zero;

  // Load A column-major: A[c*256+r] = raw[r][c]
  for (int i = tid; i < D_*D_; i += 256) {
    int c = i >> 8, r = i & 255;
    A[i] = make_double2((double)ure_raw[r*D_+c], (double)uim_raw[r*D_+c]);
  }
  __syncthreads();

  // ---- Householder factorization (zgeqr2) ----
  for (int j = 0; j < D_; ++j) {
    double part = 0.0;
    {
      int r = j + 1 + tid;
      if (r < D_) { double2 a = A[j*D_+r]; part = a.x*a.x + a.y*a.y; }
    }
    red[tid] = part; __syncthreads();
    for (int s = 128; s > 0; s >>= 1) { if (tid < s) red[tid] += red[tid+s]; __syncthreads(); }
    if (tid == 0) {
      double xnorm2 = red[0];
      double2 a = A[j*D_+j];
      if (xnorm2 == 0.0 && a.y == 0.0) {
        s_zero = 1; tau[j] = make_double2(0.0, 0.0);
      } else {
        double nrm  = sqrt(a.x*a.x + a.y*a.y + xnorm2);
        double beta = (a.x >= 0.0) ? -nrm : nrm;      // -SIGN(nrm, Re(alpha))
        double tr = (beta - a.x)/beta, ti = -a.y/beta;
        double dr = a.x - beta, di = a.y, dn = dr*dr + di*di;
        s_zero = 0; s_beta = beta; s_taur = tr; s_taui = ti;
        s_sclr = dr/dn; s_scli = -di/dn;              // 1/(alpha-beta)
        tau[j] = make_double2(tr, ti);
      }
    }
    __syncthreads();
    if (!s_zero) {
      int r = j + 1 + tid;
      if (r < D_) {
        double2 a = A[j*D_+r];
        double2 v = make_double2(a.x*s_sclr - a.y*s_scli, a.x*s_scli + a.y*s_sclr);
        A[j*D_+r] = v; sv[r] = v;
      }
      if (tid == 0) A[j*D_+j] = make_double2(s_beta, 0.0);
    }
    __syncthreads();
    if (!s_zero) {
      int k = j + 1 + tid;           // one trailing column per thread
      if (k < D_) {
        double2 ajk = A[k*D_+j];
        double wr = ajk.x, wi = ajk.y;          // v_j = 1 contribution
        for (int r = j+1; r < D_; ++r) {        // w = v^H * col
          double2 v = sv[r]; double2 c = A[k*D_+r];
          wr += v.x*c.x + v.y*c.y;
          wi += v.x*c.y - v.y*c.x;
        }
        double fr = s_taur*wr + s_taui*wi;      // f = conj(tau)*w
        double fi = s_taur*wi - s_taui*wr;
        A[k*D_+j] = make_double2(ajk.x - fr, ajk.y - fi);
        for (int r = j+1; r < D_; ++r) {
          double2 v = sv[r]; double2 c = A[k*D_+r];
          A[k*D_+r] = make_double2(c.x - (fr*v.x - fi*v.y), c.y - (fr*v.y + fi*v.x));
        }
      }
    }
    __syncthreads();
  }

  // ---- Q = H_0 H_1 ... H_255 * I (zung2r, backward application) ----
  for (int i = tid; i < D_*D_; i += 256) {
    int c = i >> 8, r = i & 255;
    Q[i] = make_double2((r == c) ? 1.0 : 0.0, 0.0);
  }
  __syncthreads();
  for (int i = D_-1; i >= 0; --i) {
    if (tid == 0) { double2 t = tau[i]; s_taur = t.x; s_taui = t.y; }
    {
      int r = i + 1 + tid;
      if (r < D_) sv[r] = A[i*D_+r];
    }
    __syncthreads();
    if (!(s_taur == 0.0 && s_taui == 0.0)) {
      int c = tid;                               // one column per thread
      double wr = Q[c*D_+i].x, wi = Q[c*D_+i].y; // v_i = 1
      for (int r = i+1; r < D_; ++r) {
        double2 v = sv[r]; double2 q = Q[c*D_+r];
        wr += v.x*q.x + v.y*q.y;
        wi += v.x*q.y - v.y*q.x;
      }
      double fr = s_taur*wr - s_taui*wi;         // f = tau * w
      double fi = s_taur*wi + s_taui*wr;
      double2 qi = Q[c*D_+i];
      Q[c*D_+i] = make_double2(qi.x - fr, qi.y - fi);
      for (int r = i+1; r < D_; ++r) {
        double2 v = sv[r]; double2 q = Q[c*D_+r];
        Q[c*D_+r] = make_double2(q.x - (fr*v.x - fi*v.y), q.y - (fr*v.y + fi*v.x));
      }
    }
    __syncthreads();
  }

  // write u as fp32 row-major [d][e]
  for (int i = tid; i < D_*D_; i += 256) {
    int e = i >> 8, d = i & 255;                 // column-major index
    u_re[d*D_+e] = (float)Q[i].x;
    u_im[d*D_+e] = (float)Q[i].y;
  }
}

// ---------------------------------------------------------------------------
// Per-(b,t,d) coefficients: decay (complex), forcing (complex), noise scale.
// ---------------------------------------------------------------------------
__global__ __launch_bounds__(256) void coef_kernel(
  const float* __restrict__ dt, const float* __restrict__ lam_re, const float* __restrict__ lam_im,
  const float* __restrict__ noise_raw,
  float* __restrict__ c_dre, float* __restrict__ c_dim, float* __restrict__ c_fre,
  float* __restrict__ c_fim, float* __restrict__ c_ns)
{
  int bt = blockIdx.x; int d = threadIdx.x;
  float dtv = dt[bt];
  float lr = lam_re[d], li = lam_im[d];
  float lam_r = fmaxf(-log1pf(expf(-lr)), -0.3f);     // -softplus(-x), clamp
  float ar = dtv*lam_r, ai = dtv*li;                  // TAU_REF_HOURS = 1
  float er = expf(ar);
  float dre = er*cosf(ai), dim_ = er*sinf(ai);
  float t = lam_r + 1e-12f;
  float sgn = (t > 0.f) ? 1.f : ((t < 0.f) ? -1.f : 0.f);
  float den_re = lam_r + 1e-8f*sgn, den_im = li;      // lam_safe
  float nr = dre - 1.f, ni = dim_;
  float d2 = den_re*den_re + den_im*den_im;
  float fre = (nr*den_re + ni*den_im)/d2;
  float fim = (ni*den_re - nr*den_im)/d2;
  float ns = sqrtf(fmaxf(dtv,0.f)) * log1pf(expf(noise_raw[d])) * 0.01f;
  int idx = bt*D_+d;
  c_dre[idx]=dre; c_dim[idx]=dim_; c_fre[idx]=fre; c_fim[idx]=fim; c_ns[idx]=ns;
}

// ---------------------------------------------------------------------------
// Encode: x_enc = x @ conj(u) => re = x@u_re, im = -(x@u_im). 64x64 tiles.
// ---------------------------------------------------------------------------
__global__ __launch_bounds__(256) void encode_kernel(
  const float* __restrict__ x, const float* __restrict__ ure, const float* __restrict__ uim,
  float* __restrict__ xer, float* __restrict__ xei)
{
  __shared__ float sA[64][65], sBr[64][65], sBi[64][65];
  int tid = threadIdx.x;
  int tx = tid & 15, ty = tid >> 4;
  int m0 = blockIdx.x * 64, n0 = blockIdx.y * 64;
  float accr[4][4] = {{0}}, acci[4][4] = {{0}};
  for (int kk = 0; kk < D_; kk += 64) {
    for (int l = tid; l < 4096; l += 256) {
      int r = l >> 6, c = l & 63;
      sA[r][c]  = x[(size_t)(m0+r)*D_ + kk + c];
      sBr[r][c] = ure[(kk+r)*D_ + n0 + c];
      sBi[r][c] = uim[(kk+r)*D_ + n0 + c];
    }
    __syncthreads();
    #pragma unroll 8
    for (int k = 0; k < 64; ++k) {
      float a[4], br[4], bi[4];
      #pragma unroll
      for (int i=0;i<4;++i) a[i] = sA[ty*4+i][k];
      #pragma unroll
      for (int j=0;j<4;++j){ br[j]=sBr[k][tx*4+j]; bi[j]=sBi[k][tx*4+j]; }
      #pragma unroll
      for (int i=0;i<4;++i)
        #pragma unroll
        for (int j=0;j<4;++j){ accr[i][j] += a[i]*br[j]; acci[i][j] += a[i]*bi[j]; }
    }
    __syncthreads();
  }
  for (int i=0;i<4;++i)
    for (int j=0;j<4;++j) {
      size_t idx = (size_t)(m0+ty*4+i)*D_ + n0 + tx*4 + j;
      xer[idx] = accr[i][j];
      xei[idx] = -acci[i][j];
    }
}

// ---------------------------------------------------------------------------
// Scan: h_t = decay*h_{t-1} + forcing*x_enc + eps*ns ; in-place over planes.
// One block per (b,n); thread = d; sequential over t.
// ---------------------------------------------------------------------------
__global__ __launch_bounds__(256) void scan_kernel(
  const float* __restrict__ eps,
  const float* __restrict__ c_dre, const float* __restrict__ c_dim,
  const float* __restrict__ c_fre, const float* __restrict__ c_fim, const float* __restrict__ c_ns,
  float* __restrict__ hre, float* __restrict__ him)
{
  int bx = blockIdx.x;
  int b = bx >> 9, n = bx & 511;
  int d = threadIdx.x;
  float hr = 0.f, hi = 0.f;
  for (int t = 0; t < T_; ++t) {
    int bt = b*T_ + t;
    int cidx = bt*D_ + d;
    float dre = c_dre[cidx], dim_ = c_dim[cidx];
    float fre = c_fre[cidx], fim = c_fim[cidx];
    float ns  = c_ns[cidx];
    size_t idx = ((size_t)bt*N_ + n)*D_ + d;
    float xr = hre[idx], xi = him[idx], ep = eps[idx];
    float br = fre*xr - fim*xi + ep*ns;
    float bi = fre*xi + fim*xr;
    float nr2 = dre*hr - dim_*hi + br;
    float ni2 = dre*hi + dim_*hr + bi;
    hr = nr2; hi = ni2;
    hre[idx] = hr; him[idx] = hi;
  }
}

// ---------------------------------------------------------------------------
// Decode: y = h @ u (complex); out plane0 = Re, plane1 = Im.
// ---------------------------------------------------------------------------
__global__ __launch_bounds__(256) void decode_kernel(
  const float* __restrict__ hre, const float* __restrict__ him,
  const float* __restrict__ ure, const float* __restrict__ uim,
  float* __restrict__ out)
{
  __shared__ float sAr[64][65], sAi[64][65], sBr[64][65], sBi[64][65];
  int tid = threadIdx.x;
  int tx = tid & 15, ty = tid >> 4;
  int m0 = blockIdx.x * 64, n0 = blockIdx.y * 64;
  float accr[4][4] = {{0}}, acci[4][4] = {{0}};
  for (int kk = 0; kk < D_; kk += 64) {
    for (int l = tid; l < 4096; l += 256) {
      int r = l >> 6, c = l & 63;
      sAr[r][c] = hre[(size_t)(m0+r)*D_ + kk + c];
      sAi[r][c] = him[(size_t)(m0+r)*D_ + kk + c];
      sBr[r][c] = ure[(kk+r)*D_ + n0 + c];
      sBi[r][c] = uim[(kk+r)*D_ + n0 + c];
    }
    __syncthreads();
    #pragma unroll 4
    for (int k = 0; k < 64; ++k) {
      float ar[4], ai[4], br[4], bi[4];
      #pragma unroll
      for (int i=0;i<4;++i){ ar[i] = sAr[ty*4+i][k]; ai[i] = sAi[ty*4+i][k]; }
      #pragma unroll
      for (int j=0;j<4;++j){ br[j]=sBr[k][tx*4+j]; bi[j]=sBi[k][tx*4+j]; }
      #pragma unroll
      for (int i=0;i<4;++i)
        #pragma unroll
        for (int j=0;j<4;++j){
          accr[i][j] += ar[i]*br[j] - ai[i]*bi[j];
          acci[i][j] += ar[i]*bi[j] + ai[i]*br[j];
        }
    }
    __syncthreads();
  }
  for (int i=0;i<4;++i)
    for (int j=0;j<4;++j) {
      size_t idx = (size_t)(m0+ty*4+i)*D_ + n0 + tx*4 + j;
      out[idx]         = accr[i][j];
      out[PLANE + idx] = acci[i][j];
    }
}

// ---------------------------------------------------------------------------
extern "C" void kernel_launch(void* const* d_in, const int* in_sizes, int n_in,
                              void* d_out, int out_size, void* d_ws, size_t ws_size,
                              hipStream_t stream)
{
  const float* x         = (const float*)d_in[0];
  const float* dt        = (const float*)d_in[1];
  const float* eps       = (const float*)d_in[2];
  const float* ure_raw   = (const float*)d_in[3];
  const float* uim_raw   = (const float*)d_in[4];
  const float* lam_re    = (const float*)d_in[5];
  const float* lam_im    = (const float*)d_in[6];
  const float* noise_raw = (const float*)d_in[7];
  float* out = (float*)d_out;

  // Workspace layout (needs ~132.3 MB; assume ws_size covers it):
  //   [0,1MB)      A (QR, double2 col-major)
  //   [1MB,2MB)    Q (double2 col-major)
  //   [2MB,+4KB)   tau
  //   [2MB+64KB..) u_re,u_im fp32 (256KB each), then 5 coef arrays (128KB each)
  //   [4MB..)      x_enc/h planes: re, im (64MB each)
  char* ws = (char*)d_ws;
  double2* A   = (double2*)(ws + 0);
  double2* Q   = (double2*)(ws + (1<<20));
  double2* tau = (double2*)(ws + (2<<20));
  float* u_re  = (float*)(ws + (2<<20) + (1<<16));
  float* u_im  = u_re + D_*D_;
  float* c_dre = u_im + D_*D_;
  float* c_dim = c_dre + B_*T_*D_;
  float* c_fre = c_dim + B_*T_*D_;
  float* c_fim = c_fre + B_*T_*D_;
  float* c_ns  = c_fim + B_*T_*D_;
  float* xer = (float*)(ws + ((size_t)4<<20));
  float* xei = xer + PLANE;

  qr_kernel<<<1, 256, 0, stream>>>(ure_raw, uim_raw, A, Q, tau, u_re, u_im);
  coef_kernel<<<B_*T_, 256, 0, stream>>>(dt, lam_re, lam_im, noise_raw,
                                         c_dre, c_dim, c_fre, c_fim, c_ns);
  encode_kernel<<<dim3(M_/64, D_/64), 256, 0, stream>>>(x, u_re, u_im, xer, xei);
  scan_kernel<<<B_*N_, 256, 0, stream>>>(eps, c_dre, c_dim, c_fre, c_fim, c_ns, xer, xei);
  decode_kernel<<<dim3(M_/64, D_/64), 256, 0, stream>>>(xer, xei, u_re, u_im, out);
}

// Round 2
// 3999.653 us; speedup vs baseline: 7.3234x; 7.3234x over previous
//
#include <hip/hip_runtime.h>
#include <math.h>

// Problem constants (B,T,N,D) = (2,64,512,256)
#define B_ 2
#define T_ 64
#define N_ 512
#define D_ 256
#define M_ (B_*T_*N_)            // 65536 rows for the GEMMs
#define PLANE ((size_t)M_*D_)    // 16777216 elements per output plane

// ---------------------------------------------------------------------------
// QR forward (zgeqr2), fp32, LAPACK convention. Single WG, 1024 threads.
// A col-major float2 in global (L2-resident, 512 KB). Trailing update is
// wave-per-column: coalesced float2 loads, in-register dot + shfl reduce.
// v kept in LDS with v[<j]=0, v[j]=1 so all loops are unmasked/uniform.
// ---------------------------------------------------------------------------
__global__ __launch_bounds__(1024) void qr_fwd_kernel(
    const float* __restrict__ ure_raw, const float* __restrict__ uim_raw,
    float2* __restrict__ A, float2* __restrict__ tau)
{
  const int t = threadIdx.x;
  const int lane = t & 63;
  const int w = t >> 6;            // wave 0..15
  __shared__ float2 sv[256];
  __shared__ float red4[4];
  __shared__ float s_taur, s_taui, s_sclr, s_scli, s_beta;

  // Load A col-major: A[c*256+r] = raw[r][c]. Coalesced reads, scattered
  // stores (absorbed by L2; one-shot 512 KB).
  for (int i = t; i < D_*D_; i += 1024) {
    int r = i >> 8, c = i & 255;
    A[c*D_ + r] = make_float2(ure_raw[r*D_+c], uim_raw[r*D_+c]);
  }
  __syncthreads();

  for (int j = 0; j < D_; ++j) {
    // ---- norm of column j below diagonal (threads 0..255, waves 0..3) ----
    float part = 0.f;
    float2 aj = make_float2(0.f, 0.f);
    if (t < 256) {
      aj = A[j*D_ + t];
      if (t > j) part = aj.x*aj.x + aj.y*aj.y;
    }
    #pragma unroll
    for (int s = 32; s > 0; s >>= 1) part += __shfl_xor(part, s);
    if (t < 256 && lane == 0) red4[w] = part;
    __syncthreads();
    if (t == 0) {
      float xn2 = red4[0] + red4[1] + red4[2] + red4[3];
      float2 al = A[j*D_ + j];
      if (xn2 == 0.f && al.y == 0.f) {
        // H = I. Make the rest of the iteration a uniform no-op.
        s_taur = 0.f; s_taui = 0.f; s_sclr = 0.f; s_scli = 0.f; s_beta = al.x;
        tau[j] = make_float2(0.f, 0.f);
      } else {
        float nrm  = sqrtf(al.x*al.x + al.y*al.y + xn2);
        float beta = (al.x >= 0.f) ? -nrm : nrm;     // -SIGN(nrm, Re(alpha))
        float tr = (beta - al.x)/beta, ti = -al.y/beta;
        float dr = al.x - beta, di = al.y, dn = dr*dr + di*di;
        s_taur = tr; s_taui = ti;
        s_sclr = dr/dn; s_scli = -di/dn;             // 1/(alpha-beta)
        s_beta = beta;
        tau[j] = make_float2(tr, ti);
      }
    }
    __syncthreads();
    // ---- form v; store to LDS and in-place into A ----
    if (t < 256) {
      float2 v;
      if (t < j)       v = make_float2(0.f, 0.f);
      else if (t == j) v = make_float2(1.f, 0.f);
      else             v = make_float2(aj.x*s_sclr - aj.y*s_scli,
                                       aj.x*s_scli + aj.y*s_sclr);
      sv[t] = v;
      if (t == j)      A[j*D_ + t] = make_float2(s_beta, 0.f);
      else if (t > j)  A[j*D_ + t] = v;
    }
    __syncthreads();
    // ---- trailing update: wave per column, rows in registers ----
    const int cmin = j >> 6;
    const float tr_ = s_taur, ti_ = s_taui;
    for (int k = j + 1 + w; k < D_; k += 16) {
      float2 q[4];
      float wr = 0.f, wi = 0.f;
      #pragma unroll
      for (int c4 = 0; c4 < 4; ++c4) {
        if (c4 >= cmin) {
          q[c4] = A[k*D_ + c4*64 + lane];
          float2 v = sv[c4*64 + lane];
          wr += v.x*q[c4].x + v.y*q[c4].y;     // w += conj(v)*a
          wi += v.x*q[c4].y - v.y*q[c4].x;
        }
      }
      #pragma unroll
      for (int s = 32; s > 0; s >>= 1) { wr += __shfl_xor(wr, s); wi += __shfl_xor(wi, s); }
      float fr = tr_*wr + ti_*wi;              // f = conj(tau)*w
      float fi = tr_*wi - ti_*wr;
      #pragma unroll
      for (int c4 = 0; c4 < 4; ++c4) {
        if (c4 >= cmin) {
          float2 v = sv[c4*64 + lane];
          q[c4].x -= fr*v.x - fi*v.y;
          q[c4].y -= fr*v.y + fi*v.x;
          A[k*D_ + c4*64 + lane] = q[c4];
        }
      }
    }
    __syncthreads();
  }
}

// ---------------------------------------------------------------------------
// QR backward (zung2r): Q columns are independent => multi-CU.
// Column c = H_0(H_1(...H_c(e_c))) (reflectors i>c are no-ops on e_c).
// One wave per column, Q column held in 4 float2 registers per lane.
// Writes u row-major fp32.
// ---------------------------------------------------------------------------
__global__ __launch_bounds__(256) void qr_bwd_kernel(
    const float2* __restrict__ A, const float2* __restrict__ tau,
    float* __restrict__ u_re, float* __restrict__ u_im)
{
  const int lane = threadIdx.x & 63;
  const int w = threadIdx.x >> 6;
  const int c = blockIdx.x * 4 + w;         // column 0..255
  float2 q[4];
  #pragma unroll
  for (int c4 = 0; c4 < 4; ++c4) {
    q[c4] = make_float2(0.f, 0.f);
    if (c4*64 + lane == c) q[c4].x = 1.f;   // q = e_c
  }
  for (int i = c; i >= 0; --i) {
    float2 tt = tau[i];
    if (tt.x == 0.f && tt.y == 0.f) continue;   // wave-uniform
    const int cmin = i >> 6;
    float wr = 0.f, wi = 0.f;
    float2 vv[4];
    #pragma unroll
    for (int c4 = 0; c4 < 4; ++c4) {
      if (c4 >= cmin) {
        int r = c4*64 + lane;
        float2 a = A[i*D_ + r];
        float2 v = (r > i) ? a : ((r == i) ? make_float2(1.f, 0.f)
                                           : make_float2(0.f, 0.f));
        vv[c4] = v;
        wr += v.x*q[c4].x + v.y*q[c4].y;    // w += conj(v)*q
        wi += v.x*q[c4].y - v.y*q[c4].x;
      }
    }
    #pragma unroll
    for (int s = 32; s > 0; s >>= 1) { wr += __shfl_xor(wr, s); wi += __shfl_xor(wi, s); }
    float fr = tt.x*wr - tt.y*wi;           // f = tau*w
    float fi = tt.x*wi + tt.y*wr;
    #pragma unroll
    for (int c4 = 0; c4 < 4; ++c4) {
      if (c4 >= cmin) {
        q[c4].x -= fr*vv[c4].x - fi*vv[c4].y;
        q[c4].y -= fr*vv[c4].y + fi*vv[c4].x;
      }
    }
  }
  // u[r][c] = Q_{r,c}
  #pragma unroll
  for (int c4 = 0; c4 < 4; ++c4) {
    int r = c4*64 + lane;
    u_re[r*D_ + c] = q[c4].x;
    u_im[r*D_ + c] = q[c4].y;
  }
}

// ---------------------------------------------------------------------------
// Per-(b,t,d) coefficients: decay (complex), forcing (complex), noise scale.
// ---------------------------------------------------------------------------
__global__ __launch_bounds__(256) void coef_kernel(
  const float* __restrict__ dt, const float* __restrict__ lam_re, const float* __restrict__ lam_im,
  const float* __restrict__ noise_raw,
  float* __restrict__ c_dre, float* __restrict__ c_dim, float* __restrict__ c_fre,
  float* __restrict__ c_fim, float* __restrict__ c_ns)
{
  int bt = blockIdx.x; int d = threadIdx.x;
  float dtv = dt[bt];
  float lr = lam_re[d], li = lam_im[d];
  float lam_r = fmaxf(-log1pf(expf(-lr)), -0.3f);     // -softplus(-x), clamp
  float ar = dtv*lam_r, ai = dtv*li;                  // TAU_REF_HOURS = 1
  float er = expf(ar);
  float dre = er*cosf(ai), dim_ = er*sinf(ai);
  float t = lam_r + 1e-12f;
  float sgn = (t > 0.f) ? 1.f : ((t < 0.f) ? -1.f : 0.f);
  float den_re = lam_r + 1e-8f*sgn, den_im = li;      // lam_safe
  float nr = dre - 1.f, ni = dim_;
  float d2 = den_re*den_re + den_im*den_im;
  float fre = (nr*den_re + ni*den_im)/d2;
  float fim = (ni*den_re - nr*den_im)/d2;
  float ns = sqrtf(fmaxf(dtv,0.f)) * log1pf(expf(noise_raw[d])) * 0.01f;
  int idx = bt*D_+d;
  c_dre[idx]=dre; c_dim[idx]=dim_; c_fre[idx]=fre; c_fim[idx]=fim; c_ns[idx]=ns;
}

// ---------------------------------------------------------------------------
// Encode: x_enc = x @ conj(u) => re = x@u_re, im = -(x@u_im). 64x64 tiles.
// ---------------------------------------------------------------------------
__global__ __launch_bounds__(256) void encode_kernel(
  const float* __restrict__ x, const float* __restrict__ ure, const float* __restrict__ uim,
  float* __restrict__ xer, float* __restrict__ xei)
{
  __shared__ float sA[64][65], sBr[64][65], sBi[64][65];
  int tid = threadIdx.x;
  int tx = tid & 15, ty = tid >> 4;
  int m0 = blockIdx.x * 64, n0 = blockIdx.y * 64;
  float accr[4][4] = {{0}}, acci[4][4] = {{0}};
  for (int kk = 0; kk < D_; kk += 64) {
    for (int l = tid; l < 4096; l += 256) {
      int r = l >> 6, c = l & 63;
      sA[r][c]  = x[(size_t)(m0+r)*D_ + kk + c];
      sBr[r][c] = ure[(kk+r)*D_ + n0 + c];
      sBi[r][c] = uim[(kk+r)*D_ + n0 + c];
    }
    __syncthreads();
    #pragma unroll 8
    for (int k = 0; k < 64; ++k) {
      float a[4], br[4], bi[4];
      #pragma unroll
      for (int i=0;i<4;++i) a[i] = sA[ty*4+i][k];
      #pragma unroll
      for (int j=0;j<4;++j){ br[j]=sBr[k][tx*4+j]; bi[j]=sBi[k][tx*4+j]; }
      #pragma unroll
      for (int i=0;i<4;++i)
        #pragma unroll
        for (int j=0;j<4;++j){ accr[i][j] += a[i]*br[j]; acci[i][j] += a[i]*bi[j]; }
    }
    __syncthreads();
  }
  for (int i=0;i<4;++i)
    for (int j=0;j<4;++j) {
      size_t idx = (size_t)(m0+ty*4+i)*D_ + n0 + tx*4 + j;
      xer[idx] = accr[i][j];
      xei[idx] = -acci[i][j];
    }
}

// ---------------------------------------------------------------------------
// Scan: h_t = decay*h_{t-1} + forcing*x_enc + eps*ns ; in-place over planes.
// One block per (b,n); thread = d; sequential over t.
// ---------------------------------------------------------------------------
__global__ __launch_bounds__(256) void scan_kernel(
  const float* __restrict__ eps,
  const float* __restrict__ c_dre, const float* __restrict__ c_dim,
  const float* __restrict__ c_fre, const float* __restrict__ c_fim, const float* __restrict__ c_ns,
  float* __restrict__ hre, float* __restrict__ him)
{
  int bx = blockIdx.x;
  int b = bx >> 9, n = bx & 511;
  int d = threadIdx.x;
  float hr = 0.f, hi = 0.f;
  for (int t = 0; t < T_; ++t) {
    int bt = b*T_ + t;
    int cidx = bt*D_ + d;
    float dre = c_dre[cidx], dim_ = c_dim[cidx];
    float fre = c_fre[cidx], fim = c_fim[cidx];
    float ns  = c_ns[cidx];
    size_t idx = ((size_t)bt*N_ + n)*D_ + d;
    float xr = hre[idx], xi = him[idx], ep = eps[idx];
    float br = fre*xr - fim*xi + ep*ns;
    float bi = fre*xi + fim*xr;
    float nr2 = dre*hr - dim_*hi + br;
    float ni2 = dre*hi + dim_*hr + bi;
    hr = nr2; hi = ni2;
    hre[idx] = hr; him[idx] = hi;
  }
}

// ---------------------------------------------------------------------------
// Decode: y = h @ u (complex); out plane0 = Re, plane1 = Im.
// ---------------------------------------------------------------------------
__global__ __launch_bounds__(256) void decode_kernel(
  const float* __restrict__ hre, const float* __restrict__ him,
  const float* __restrict__ ure, const float* __restrict__ uim,
  float* __restrict__ out)
{
  __shared__ float sAr[64][65], sAi[64][65], sBr[64][65], sBi[64][65];
  int tid = threadIdx.x;
  int tx = tid & 15, ty = tid >> 4;
  int m0 = blockIdx.x * 64, n0 = blockIdx.y * 64;
  float accr[4][4] = {{0}}, acci[4][4] = {{0}};
  for (int kk = 0; kk < D_; kk += 64) {
    for (int l = tid; l < 4096; l += 256) {
      int r = l >> 6, c = l & 63;
      sAr[r][c] = hre[(size_t)(m0+r)*D_ + kk + c];
      sAi[r][c] = him[(size_t)(m0+r)*D_ + kk + c];
      sBr[r][c] = ure[(kk+r)*D_ + n0 + c];
      sBi[r][c] = uim[(kk+r)*D_ + n0 + c];
    }
    __syncthreads();
    #pragma unroll 4
    for (int k = 0; k < 64; ++k) {
      float ar[4], ai[4], br[4], bi[4];
      #pragma unroll
      for (int i=0;i<4;++i){ ar[i] = sAr[ty*4+i][k]; ai[i] = sAi[ty*4+i][k]; }
      #pragma unroll
      for (int j=0;j<4;++j){ br[j]=sBr[k][tx*4+j]; bi[j]=sBi[k][tx*4+j]; }
      #pragma unroll
      for (int i=0;i<4;++i)
        #pragma unroll
        for (int j=0;j<4;++j){
          accr[i][j] += ar[i]*br[j] - ai[i]*bi[j];
          acci[i][j] += ar[i]*bi[j] + ai[i]*br[j];
        }
    }
    __syncthreads();
  }
  for (int i=0;i<4;++i)
    for (int j=0;j<4;++j) {
      size_t idx = (size_t)(m0+ty*4+i)*D_ + n0 + tx*4 + j;
      out[idx]         = accr[i][j];
      out[PLANE + idx] = acci[i][j];
    }
}

// ---------------------------------------------------------------------------
extern "C" void kernel_launch(void* const* d_in, const int* in_sizes, int n_in,
                              void* d_out, int out_size, void* d_ws, size_t ws_size,
                              hipStream_t stream)
{
  const float* x         = (const float*)d_in[0];
  const float* dt        = (const float*)d_in[1];
  const float* eps       = (const float*)d_in[2];
  const float* ure_raw   = (const float*)d_in[3];
  const float* uim_raw   = (const float*)d_in[4];
  const float* lam_re    = (const float*)d_in[5];
  const float* lam_im    = (const float*)d_in[6];
  const float* noise_raw = (const float*)d_in[7];
  float* out = (float*)d_out;

  // Workspace layout:
  //   [0, 512K)        A (float2 col-major, QR workspace / V+R)
  //   [512K, 512K+2K)  tau (float2[256])
  //   [1M, 1.25M)      u_re fp32 row-major
  //   [1.25M, 1.5M)    u_im
  //   [1.5M, ...)      coef arrays (5 x 128 KB)
  //   [4M, 4M+128M)    x_enc / h planes (re, im), 64 MB each
  char* ws = (char*)d_ws;
  float2* A   = (float2*)(ws);
  float2* tau = (float2*)(ws + (512<<10));
  float* u_re = (float*)(ws + (1<<20));
  float* u_im = u_re + D_*D_;
  float* c_dre = u_im + D_*D_;
  float* c_dim = c_dre + B_*T_*D_;
  float* c_fre = c_dim + B_*T_*D_;
  float* c_fim = c_fre + B_*T_*D_;
  float* c_ns  = c_fim + B_*T_*D_;
  float* xer = (float*)(ws + ((size_t)4<<20));
  float* xei = xer + PLANE;

  qr_fwd_kernel<<<1, 1024, 0, stream>>>(ure_raw, uim_raw, A, tau);
  qr_bwd_kernel<<<64, 256, 0, stream>>>(A, tau, u_re, u_im);
  coef_kernel<<<B_*T_, 256, 0, stream>>>(dt, lam_re, lam_im, noise_raw,
                                         c_dre, c_dim, c_fre, c_fim, c_ns);
  encode_kernel<<<dim3(M_/64, D_/64), 256, 0, stream>>>(x, u_re, u_im, xer, xei);
  scan_kernel<<<B_*N_, 256, 0, stream>>>(eps, c_dre, c_dim, c_fre, c_fim, c_ns, xer, xei);
  decode_kernel<<<dim3(M_/64, D_/64), 256, 0, stream>>>(xer, xei, u_re, u_im, out);
}

// Round 3
// 1615.153 us; speedup vs baseline: 18.1351x; 2.4763x over previous
//
#include <hip/hip_runtime.h>
#include <math.h>

// Problem constants (B,T,N,D) = (2,64,512,256)
#define B_ 2
#define T_ 64
#define N_ 512
#define D_ 256
#define M_ (B_*T_*N_)            // 65536 rows for the GEMMs
#define PLANE ((size_t)M_*D_)    // 16777216 elements per output plane

typedef unsigned short u16;
typedef __attribute__((ext_vector_type(8))) short bf16x8;
typedef __attribute__((ext_vector_type(4))) float f32x4;

__device__ __forceinline__ u16 f2bf(float f) {
  union { float f; unsigned u; } cv; cv.f = f;
  unsigned u = cv.u;
  return (u16)((u + 0x7FFFu + ((u >> 16) & 1u)) >> 16);   // RNE
}
__device__ __forceinline__ float bf2f(u16 h) {
  union { unsigned u; float f; } cv; cv.u = ((unsigned)h) << 16;
  return cv.f;
}

// ---------------------------------------------------------------------------
// A init: col-major float2 A[c*256+r] = raw[r][c]
// ---------------------------------------------------------------------------
__global__ __launch_bounds__(1024) void qr_init_kernel(
    const float* __restrict__ ure_raw, const float* __restrict__ uim_raw,
    float2* __restrict__ A)
{
  int i = blockIdx.x * 1024 + threadIdx.x;   // 64 blocks
  int c = i >> 8, r = i & 255;
  A[i] = make_float2(ure_raw[r*D_ + c], uim_raw[r*D_ + c]);
}

// ---------------------------------------------------------------------------
// Panel factorization (zgeqr2 on cols j0..j0+31, rows j0..255), LAPACK
// convention, fp32. 256 threads = 4 waves; wave w owns cols {w, w+4, ...}
// of the panel, each column in 4 float2 registers per lane. v broadcast via
// LDS. Numerically identical reflector sequence to the unblocked version.
// ---------------------------------------------------------------------------
__global__ __launch_bounds__(256) void qr_panel_kernel(
    float2* __restrict__ A, float2* __restrict__ tau, int j0)
{
  const int tid = threadIdx.x, lane = tid & 63, w = tid >> 6;
  const int R = 256 - j0;
  __shared__ float2 sv[256];
  __shared__ float2 stau;
  float2 col[8][4];

  #pragma unroll
  for (int lc = 0; lc < 8; ++lc) {
    int cg = j0 + lc*4 + w;
    #pragma unroll
    for (int m = 0; m < 4; ++m) {
      int rr = m*64 + lane;
      col[lc][m] = (rr < R) ? A[cg*D_ + j0 + rr] : make_float2(0.f, 0.f);
    }
  }

  for (int jl = 0; jl < 32; ++jl) {
    const int wo = jl & 3, ljc = jl >> 2;
    if (w == wo) {
      float2 dcol[4];
      #pragma unroll
      for (int lc = 0; lc < 8; ++lc)
        if (lc == ljc) { dcol[0]=col[lc][0]; dcol[1]=col[lc][1];
                         dcol[2]=col[lc][2]; dcol[3]=col[lc][3]; }
      float part = 0.f;
      #pragma unroll
      for (int m = 0; m < 4; ++m) {
        int rr = m*64 + lane;
        if (rr > jl && rr < R) part += dcol[m].x*dcol[m].x + dcol[m].y*dcol[m].y;
      }
      #pragma unroll
      for (int s = 32; s; s >>= 1) part += __shfl_xor(part, s);
      float ar = __shfl(dcol[0].x, jl), ai = __shfl(dcol[0].y, jl);
      float taur, taui, sclr, scli;
      if (part == 0.f && ai == 0.f) {
        taur = taui = sclr = scli = 0.f;
      } else {
        float nrm  = sqrtf(ar*ar + ai*ai + part);
        float beta = (ar >= 0.f) ? -nrm : nrm;     // -SIGN(nrm, Re(alpha))
        taur = (beta - ar)/beta; taui = -ai/beta;
        float dr = ar - beta, di = ai, dn = dr*dr + di*di;
        sclr = dr/dn; scli = -di/dn;               // 1/(alpha-beta)
      }
      #pragma unroll
      for (int m = 0; m < 4; ++m) {
        int rr = m*64 + lane;
        float2 a = dcol[m], v;
        if (rr > jl)      v = make_float2(a.x*sclr - a.y*scli, a.x*scli + a.y*sclr);
        else if (rr == jl) v = make_float2(1.f, 0.f);
        else              v = make_float2(0.f, 0.f);
        dcol[m] = v;
        sv[rr] = v;
      }
      #pragma unroll
      for (int lc = 0; lc < 8; ++lc)
        if (lc == ljc) { col[lc][0]=dcol[0]; col[lc][1]=dcol[1];
                         col[lc][2]=dcol[2]; col[lc][3]=dcol[3]; }
      if (lane == 0) { stau = make_float2(taur, taui);
                       tau[j0+jl] = make_float2(taur, taui); }
    }
    __syncthreads();
    const float taur = stau.x, taui = stau.y;
    float2 v[4];
    #pragma unroll
    for (int m = 0; m < 4; ++m) v[m] = sv[m*64 + lane];
    float wr[8], wi[8];
    #pragma unroll
    for (int lc = 0; lc < 8; ++lc) {
      int cl = lc*4 + w;
      wr[lc] = 0.f; wi[lc] = 0.f;
      if (cl > jl) {
        #pragma unroll
        for (int m = 0; m < 4; ++m) {
          float2 a = col[lc][m];
          wr[lc] += v[m].x*a.x + v[m].y*a.y;     // w += conj(v)*a
          wi[lc] += v[m].x*a.y - v[m].y*a.x;
        }
      }
    }
    #pragma unroll
    for (int lc = 0; lc < 8; ++lc) {
      #pragma unroll
      for (int s = 32; s; s >>= 1) { wr[lc] += __shfl_xor(wr[lc], s);
                                     wi[lc] += __shfl_xor(wi[lc], s); }
    }
    #pragma unroll
    for (int lc = 0; lc < 8; ++lc) {
      int cl = lc*4 + w;
      if (cl > jl) {
        float fr = taur*wr[lc] + taui*wi[lc];    // f = conj(tau)*w
        float fi = taur*wi[lc] - taui*wr[lc];
        #pragma unroll
        for (int m = 0; m < 4; ++m) {
          col[lc][m].x -= fr*v[m].x - fi*v[m].y;
          col[lc][m].y -= fr*v[m].y + fi*v[m].x;
        }
      }
    }
    __syncthreads();
  }

  #pragma unroll
  for (int lc = 0; lc < 8; ++lc) {
    int cg = j0 + lc*4 + w;
    #pragma unroll
    for (int m = 0; m < 4; ++m) {
      int rr = m*64 + lane;
      if (rr < R) A[cg*D_ + j0 + rr] = col[lc][m];
    }
  }
}

// ---------------------------------------------------------------------------
// Apply panel j0's 32 reflectors to a 32-column trailing tile (registers).
// blockIdx.x selects the tile; v streamed from L2 per reflector per wave.
// f = conj(tau)*w; tau==0 degenerates to a no-op (f=0), no branch needed.
// ---------------------------------------------------------------------------
__global__ __launch_bounds__(256) void qr_apply_kernel(
    float2* __restrict__ A, const float2* __restrict__ tau, int j0)
{
  const int tid = threadIdx.x, lane = tid & 63, w = tid >> 6;
  const int R = 256 - j0;
  const int c0 = j0 + 32 + blockIdx.x * 32;
  float2 col[8][4];
  #pragma unroll
  for (int lc = 0; lc < 8; ++lc) {
    int cg = c0 + lc*4 + w;
    #pragma unroll
    for (int m = 0; m < 4; ++m) {
      int rr = m*64 + lane;
      col[lc][m] = (rr < R) ? A[cg*D_ + j0 + rr] : make_float2(0.f, 0.f);
    }
  }
  for (int jl = 0; jl < 32; ++jl) {
    float2 tt = tau[j0 + jl];
    float2 v[4];
    #pragma unroll
    for (int m = 0; m < 4; ++m) {
      int rr = m*64 + lane;
      float2 raw = (rr < R) ? A[(j0+jl)*D_ + j0 + rr] : make_float2(0.f, 0.f);
      v[m] = (rr > jl) ? raw
           : ((rr == jl) ? make_float2(1.f, 0.f) : make_float2(0.f, 0.f));
    }
    float wr[8], wi[8];
    #pragma unroll
    for (int lc = 0; lc < 8; ++lc) {
      wr[lc] = 0.f; wi[lc] = 0.f;
      #pragma unroll
      for (int m = 0; m < 4; ++m) {
        float2 a = col[lc][m];
        wr[lc] += v[m].x*a.x + v[m].y*a.y;
        wi[lc] += v[m].x*a.y - v[m].y*a.x;
      }
    }
    #pragma unroll
    for (int lc = 0; lc < 8; ++lc) {
      #pragma unroll
      for (int s = 32; s; s >>= 1) { wr[lc] += __shfl_xor(wr[lc], s);
                                     wi[lc] += __shfl_xor(wi[lc], s); }
    }
    #pragma unroll
    for (int lc = 0; lc < 8; ++lc) {
      float fr = tt.x*wr[lc] + tt.y*wi[lc];
      float fi = tt.x*wi[lc] - tt.y*wr[lc];
      #pragma unroll
      for (int m = 0; m < 4; ++m) {
        col[lc][m].x -= fr*v[m].x - fi*v[m].y;
        col[lc][m].y -= fr*v[m].y + fi*v[m].x;
      }
    }
  }
  #pragma unroll
  for (int lc = 0; lc < 8; ++lc) {
    int cg = c0 + lc*4 + w;
    #pragma unroll
    for (int m = 0; m < 4; ++m) {
      int rr = m*64 + lane;
      if (rr < R) A[cg*D_ + j0 + rr] = col[lc][m];
    }
  }
}

// ---------------------------------------------------------------------------
// zung2r: column c of Q = H_0(...H_c(e_c)); one wave per column.
// Epilogue writes the bf16 B^T matrices for both GEMMs directly:
//   Benc [512][256]: rows 0..255 = Re(Q)^T, rows 256.. = Im(Q)^T
//   Bdec [512][512]: [n][k]      : n<256,k<256: ur[k][n]; n<256,k>=256: -ui
//                     n>=256,k<256: ui;          n>=256,k>=256: ur
// ---------------------------------------------------------------------------
__global__ __launch_bounds__(256) void qr_bwd_kernel(
    const float2* __restrict__ A, const float2* __restrict__ tau,
    u16* __restrict__ Benc, u16* __restrict__ Bdec)
{
  const int lane = threadIdx.x & 63;
  const int w = threadIdx.x >> 6;
  const int c = blockIdx.x * 4 + w;
  float2 q[4];
  #pragma unroll
  for (int m = 0; m < 4; ++m) {
    q[m] = make_float2(0.f, 0.f);
    if (m*64 + lane == c) q[m].x = 1.f;
  }
  for (int i = c; i >= 0; --i) {
    float2 tt = tau[i];
    if (tt.x == 0.f && tt.y == 0.f) continue;
    float wr = 0.f, wi = 0.f;
    float2 vv[4];
    #pragma unroll
    for (int m = 0; m < 4; ++m) {
      int r = m*64 + lane;
      float2 a = A[i*D_ + r];
      float2 v = (r > i) ? a : ((r == i) ? make_float2(1.f, 0.f)
                                         : make_float2(0.f, 0.f));
      vv[m] = v;
      wr += v.x*q[m].x + v.y*q[m].y;
      wi += v.x*q[m].y - v.y*q[m].x;
    }
    #pragma unroll
    for (int s = 32; s; s >>= 1) { wr += __shfl_xor(wr, s); wi += __shfl_xor(wi, s); }
    float fr = tt.x*wr - tt.y*wi;             // f = tau*w
    float fi = tt.x*wi + tt.y*wr;
    #pragma unroll
    for (int m = 0; m < 4; ++m) {
      q[m].x -= fr*vv[m].x - fi*vv[m].y;
      q[m].y -= fr*vv[m].y + fi*vv[m].x;
    }
  }
  #pragma unroll
  for (int m = 0; m < 4; ++m) {
    int r = m*64 + lane;
    u16 qre = f2bf(q[m].x), qim = f2bf(q[m].y), qimn = f2bf(-q[m].y);
    Benc[(size_t)c*D_ + r]          = qre;
    Benc[(size_t)(c+256)*D_ + r]    = qim;
    Bdec[(size_t)c*512 + r]         = qre;
    Bdec[(size_t)c*512 + 256 + r]   = qimn;
    Bdec[(size_t)(c+256)*512 + r]       = qim;
    Bdec[(size_t)(c+256)*512 + 256 + r] = qre;
  }
}

// ---------------------------------------------------------------------------
// Per-(b,t,d) coefficients.
// ---------------------------------------------------------------------------
__global__ __launch_bounds__(256) void coef_kernel(
  const float* __restrict__ dt, const float* __restrict__ lam_re, const float* __restrict__ lam_im,
  const float* __restrict__ noise_raw,
  float* __restrict__ c_dre, float* __restrict__ c_dim, float* __restrict__ c_fre,
  float* __restrict__ c_fim, float* __restrict__ c_ns)
{
  int bt = blockIdx.x; int d = threadIdx.x;
  float dtv = dt[bt];
  float lr = lam_re[d], li = lam_im[d];
  float lam_r = fmaxf(-log1pf(expf(-lr)), -0.3f);
  float ar = dtv*lam_r, ai = dtv*li;
  float er = expf(ar);
  float dre = er*cosf(ai), dim_ = er*sinf(ai);
  float t = lam_r + 1e-12f;
  float sgn = (t > 0.f) ? 1.f : ((t < 0.f) ? -1.f : 0.f);
  float den_re = lam_r + 1e-8f*sgn, den_im = li;
  float nr = dre - 1.f, ni = dim_;
  float d2 = den_re*den_re + den_im*den_im;
  float fre = (nr*den_re + ni*den_im)/d2;
  float fim = (ni*den_re - nr*den_im)/d2;
  float ns = sqrtf(fmaxf(dtv,0.f)) * log1pf(expf(noise_raw[d])) * 0.01f;
  int idx = bt*D_+d;
  c_dre[idx]=dre; c_dim[idx]=dim_; c_fre[idx]=fre; c_fim[idx]=fim; c_ns[idx]=ns;
}

// ---------------------------------------------------------------------------
// x fp32 -> bf16
// ---------------------------------------------------------------------------
__global__ __launch_bounds__(256) void xconv_kernel(
    const float4* __restrict__ x, ushort4* __restrict__ x16)
{
  const size_t n4 = PLANE/4;
  for (size_t i = blockIdx.x*256 + threadIdx.x; i < n4; i += (size_t)2048*256) {
    float4 v = x[i];
    ushort4 o;
    o.x = f2bf(v.x); o.y = f2bf(v.y); o.z = f2bf(v.z); o.w = f2bf(v.w);
    x16[i] = o;
  }
}

// ---------------------------------------------------------------------------
// bf16 MFMA GEMM, 128x128 tile, 4 waves, BK=64, 16x16x32 MFMA.
// A [M][K] bf16 row-major (1 or 2 planes), B supplied transposed [N][K].
// LDS row stride 72 elements (144 B): 16B-aligned, 2-way banks (free).
// ---------------------------------------------------------------------------
#define LDT 72

__global__ __launch_bounds__(256) void encode_gemm(
    const u16* __restrict__ x16, const u16* __restrict__ Bt,
    u16* __restrict__ xer16, u16* __restrict__ xei16)
{
  __shared__ u16 sA[128*LDT];
  __shared__ u16 sB[128*LDT];
  const int tid = threadIdx.x;
  const int lane = tid & 63, w = tid >> 6;
  const int wr = w >> 1, wc = w & 1;
  const int l15 = lane & 15, l4 = lane >> 4;
  const int m0 = blockIdx.x * 128;
  const int n0 = blockIdx.y * 128;
  f32x4 acc[4][4] = {};
  for (int kb = 0; kb < 4; ++kb) {
    #pragma unroll
    for (int i = 0; i < 4; ++i) {
      int chunk = i*256 + tid;
      int row = chunk >> 3, k0 = (chunk & 7) * 8;
      int4 va = *(const int4*)(x16 + (size_t)(m0+row)*D_ + kb*64 + k0);
      int4 vb = *(const int4*)(Bt  + (size_t)(n0+row)*D_ + kb*64 + k0);
      *(int4*)&sA[row*LDT + k0] = va;
      *(int4*)&sB[row*LDT + k0] = vb;
    }
    __syncthreads();
    #pragma unroll
    for (int ks = 0; ks < 2; ++ks) {
      bf16x8 af[4], bb[4];
      #pragma unroll
      for (int mf = 0; mf < 4; ++mf)
        af[mf] = *(const bf16x8*)&sA[(wr*64 + mf*16 + l15)*LDT + ks*32 + l4*8];
      #pragma unroll
      for (int nf = 0; nf < 4; ++nf)
        bb[nf] = *(const bf16x8*)&sB[(wc*64 + nf*16 + l15)*LDT + ks*32 + l4*8];
      #pragma unroll
      for (int mf = 0; mf < 4; ++mf)
        #pragma unroll
        for (int nf = 0; nf < 4; ++nf)
          acc[mf][nf] = __builtin_amdgcn_mfma_f32_16x16x32_bf16(
              af[mf], bb[nf], acc[mf][nf], 0, 0, 0);
    }
    __syncthreads();
  }
  #pragma unroll
  for (int mf = 0; mf < 4; ++mf)
    #pragma unroll
    for (int nf = 0; nf < 4; ++nf)
      #pragma unroll
      for (int r = 0; r < 4; ++r) {
        int row = m0 + wr*64 + mf*16 + l4*4 + r;
        int col = n0 + wc*64 + nf*16 + l15;
        float v = acc[mf][nf][r];
        if (col < 256) xer16[(size_t)row*D_ + col] = f2bf(v);
        else           xei16[(size_t)row*D_ + col - 256] = f2bf(-v);
      }
}

__global__ __launch_bounds__(256) void decode_gemm(
    const u16* __restrict__ hre16, const u16* __restrict__ him16,
    const u16* __restrict__ Bt, float* __restrict__ out)
{
  __shared__ u16 sA[128*LDT];
  __shared__ u16 sB[128*LDT];
  const int tid = threadIdx.x;
  const int lane = tid & 63, w = tid >> 6;
  const int wr = w >> 1, wc = w & 1;
  const int l15 = lane & 15, l4 = lane >> 4;
  const int m0 = blockIdx.x * 128;
  const int n0 = blockIdx.y * 128;
  f32x4 acc[4][4] = {};
  for (int kb = 0; kb < 8; ++kb) {
    const u16* aplane = (kb < 4) ? hre16 : him16;
    const int kk = (kb & 3) * 64;
    #pragma unroll
    for (int i = 0; i < 4; ++i) {
      int chunk = i*256 + tid;
      int row = chunk >> 3, k0 = (chunk & 7) * 8;
      int4 va = *(const int4*)(aplane + (size_t)(m0+row)*D_ + kk + k0);
      int4 vb = *(const int4*)(Bt + (size_t)(n0+row)*512 + kb*64 + k0);
      *(int4*)&sA[row*LDT + k0] = va;
      *(int4*)&sB[row*LDT + k0] = vb;
    }
    __syncthreads();
    #pragma unroll
    for (int ks = 0; ks < 2; ++ks) {
      bf16x8 af[4], bb[4];
      #pragma unroll
      for (int mf = 0; mf < 4; ++mf)
        af[mf] = *(const bf16x8*)&sA[(wr*64 + mf*16 + l15)*LDT + ks*32 + l4*8];
      #pragma unroll
      for (int nf = 0; nf < 4; ++nf)
        bb[nf] = *(const bf16x8*)&sB[(wc*64 + nf*16 + l15)*LDT + ks*32 + l4*8];
      #pragma unroll
      for (int mf = 0; mf < 4; ++mf)
        #pragma unroll
        for (int nf = 0; nf < 4; ++nf)
          acc[mf][nf] = __builtin_amdgcn_mfma_f32_16x16x32_bf16(
              af[mf], bb[nf], acc[mf][nf], 0, 0, 0);
    }
    __syncthreads();
  }
  #pragma unroll
  for (int mf = 0; mf < 4; ++mf)
    #pragma unroll
    for (int nf = 0; nf < 4; ++nf)
      #pragma unroll
      for (int r = 0; r < 4; ++r) {
        int row = m0 + wr*64 + mf*16 + l4*4 + r;
        int col = n0 + wc*64 + nf*16 + l15;
        float v = acc[mf][nf][r];
        if (col < 256) out[(size_t)row*D_ + col] = v;
        else           out[PLANE + (size_t)row*D_ + col - 256] = v;
      }
}

// ---------------------------------------------------------------------------
// Scan: reads bf16 x_enc planes, fp32 eps/coefs; writes bf16 h planes.
// ---------------------------------------------------------------------------
__global__ __launch_bounds__(256) void scan_kernel(
  const float* __restrict__ eps,
  const float* __restrict__ c_dre, const float* __restrict__ c_dim,
  const float* __restrict__ c_fre, const float* __restrict__ c_fim, const float* __restrict__ c_ns,
  const u16* __restrict__ xer16, const u16* __restrict__ xei16,
  u16* __restrict__ hre16, u16* __restrict__ him16)
{
  int bx = blockIdx.x;
  int b = bx >> 9, n = bx & 511;
  int d = threadIdx.x;
  float hr = 0.f, hi = 0.f;
  for (int t = 0; t < T_; ++t) {
    int bt = b*T_ + t;
    int cidx = bt*D_ + d;
    float dre = c_dre[cidx], dim_ = c_dim[cidx];
    float fre = c_fre[cidx], fim = c_fim[cidx];
    float ns  = c_ns[cidx];
    size_t idx = ((size_t)bt*N_ + n)*D_ + d;
    float xr = bf2f(xer16[idx]), xi = bf2f(xei16[idx]), ep = eps[idx];
    float br = fre*xr - fim*xi + ep*ns;
    float bi = fre*xi + fim*xr;
    float nr2 = dre*hr - dim_*hi + br;
    float ni2 = dre*hi + dim_*hr + bi;
    hr = nr2; hi = ni2;
    hre16[idx] = f2bf(hr); him16[idx] = f2bf(hi);
  }
}

// ---------------------------------------------------------------------------
extern "C" void kernel_launch(void* const* d_in, const int* in_sizes, int n_in,
                              void* d_out, int out_size, void* d_ws, size_t ws_size,
                              hipStream_t stream)
{
  const float* x         = (const float*)d_in[0];
  const float* dt        = (const float*)d_in[1];
  const float* eps       = (const float*)d_in[2];
  const float* ure_raw   = (const float*)d_in[3];
  const float* uim_raw   = (const float*)d_in[4];
  const float* lam_re    = (const float*)d_in[5];
  const float* lam_im    = (const float*)d_in[6];
  const float* noise_raw = (const float*)d_in[7];
  float* out = (float*)d_out;

  // ws layout (132 MB total):
  //   0       A float2[65536]            512 KB
  //   512K    tau float2[256]
  //   1M      Benc bf16 [512][256]       256 KB
  //   1.5M    Bdec bf16 [512][512]       512 KB
  //   2M      coefs 5 x 128 KB
  //   4M      x16 bf16 [M][256]  32 MB   (reused as hre16 after encode)
  //   36M     xer16 32 MB
  //   68M     xei16 32 MB
  //   100M    him16 32 MB
  char* ws = (char*)d_ws;
  float2* A    = (float2*)(ws);
  float2* tau  = (float2*)(ws + 524288);
  u16* Benc    = (u16*)(ws + (1<<20));
  u16* Bdec    = (u16*)(ws + 1572864);
  float* c_dre = (float*)(ws + (2<<20));
  float* c_dim = c_dre + B_*T_*D_;
  float* c_fre = c_dim + B_*T_*D_;
  float* c_fim = c_fre + B_*T_*D_;
  float* c_ns  = c_fim + B_*T_*D_;
  u16* x16     = (u16*)(ws + ((size_t)4<<20));
  u16* xer16   = (u16*)(ws + ((size_t)36<<20));
  u16* xei16   = (u16*)(ws + ((size_t)68<<20));
  u16* hre16   = x16;
  u16* him16   = (u16*)(ws + ((size_t)100<<20));

  qr_init_kernel<<<64, 1024, 0, stream>>>(ure_raw, uim_raw, A);
  for (int p = 0; p < 8; ++p) {
    qr_panel_kernel<<<1, 256, 0, stream>>>(A, tau, 32*p);
    int nb = 7 - p;
    if (nb > 0) qr_apply_kernel<<<nb, 256, 0, stream>>>(A, tau, 32*p);
  }
  qr_bwd_kernel<<<64, 256, 0, stream>>>(A, tau, Benc, Bdec);
  coef_kernel<<<B_*T_, 256, 0, stream>>>(dt, lam_re, lam_im, noise_raw,
                                         c_dre, c_dim, c_fre, c_fim, c_ns);
  xconv_kernel<<<2048, 256, 0, stream>>>((const float4*)x, (ushort4*)x16);
  encode_gemm<<<dim3(M_/128, 4), 256, 0, stream>>>(x16, Benc, xer16, xei16);
  scan_kernel<<<B_*N_, 256, 0, stream>>>(eps, c_dre, c_dim, c_fre, c_fim, c_ns,
                                         xer16, xei16, hre16, him16);
  decode_gemm<<<dim3(M_/128, 4), 256, 0, stream>>>(hre16, him16, Bdec, out);
}